// Round 9
// baseline (187.390 us; speedup 1.0000x reference)
//
#include <hip/hip_runtime.h>
#include <hip/hip_bf16.h>
#include <math.h>

#define ALPHA 0.2f
#define LOG2E 1.4426950408889634f

constexpr int B_ = 4, N_ = 2048, F_ = 256, T_ = 8, H_ = 4, D_ = 64;
constexpr int FT = F_ + T_; // 264

using half8   = __attribute__((ext_vector_type(8))) _Float16;
using float4v = __attribute__((ext_vector_type(4))) float;
using uint4v  = __attribute__((ext_vector_type(4))) unsigned;

#if __has_builtin(__builtin_amdgcn_exp2f)
#define EXP2F(x) __builtin_amdgcn_exp2f(x)
#else
#define EXP2F(x) exp2f(x)
#endif

__device__ inline unsigned pkrtz_u(float a, float b) {
    return __builtin_bit_cast(unsigned, __builtin_amdgcn_cvt_pkrtz(a, b));
}

// ---- workspace byte offsets (16B aligned; total <= 9314560 B == r8 passing footprint) ----
#define V1_OFF    0u          // 4*264 f32
#define V2_OFF    4224u       // 4*264 f32
#define E1A_OFF   8448u       // [b][h][n] float2 {P1,N1} fp32        (256 KB)
#define E2A_OFF   270592u     // [b][h][n] float2 {P2,N2} fp32        (256 KB)
#define PARTS_OFF 794880u     // 16 x [b][h][n] f32 partial colsums   (2 MB)
#define WT_OFF    2892032u    // 256*256 fp16 : W^T [hd][f]           (128 KB)
#define BITS_OFF  3023104u    // [b][i][64 words] adj bitmask         (2 MB)
#define WHT_OFF   5120256u    // [b][hd][j] fp16 Wh^T                 (4 MB)
// end: 9314560

__device__ inline void gl2lds16(const void* g, void* l) {
    __builtin_amdgcn_global_load_lds(
        (const __attribute__((address_space(1))) unsigned*)g,
        (__attribute__((address_space(3))) unsigned*)l, 16, 0, 0);
}

// K1 (fused pre): blocks [0,65536): adjpack; [65536, 65536+265): WT cast + v1/v2.
__global__ __launch_bounds__(256) void k_pre(const int* __restrict__ adj,
                                             const float* __restrict__ Wq,
                                             const float* __restrict__ Wk,
                                             const float* __restrict__ a,
                                             const float* __restrict__ W,
                                             unsigned* __restrict__ bits,
                                             float* __restrict__ v1,
                                             float* __restrict__ v2,
                                             _Float16* __restrict__ WT) {
    if (blockIdx.x < 65536u) {
        // adjpack: 64 MB coalesced read -> 2 MB bitmask (ballot)
        size_t tid = (size_t)blockIdx.x * 256 + threadIdx.x;
        int av = adj[tid];
        unsigned long long msk = __ballot(av != 0);
        int lane = threadIdx.x & 63;
        if (lane == 0)       bits[tid >> 5] = (unsigned)msk;
        else if (lane == 32) bits[tid >> 5] = (unsigned)(msk >> 32);
        return;
    }
    int gid = (blockIdx.x - 65536) * 256 + threadIdx.x;
    if (gid < 65536) {
        int hd = gid >> 8, f = gid & 255;
        int h = hd >> 6, d = hd & 63;
        WT[(size_t)hd * F_ + f] = (_Float16)W[((size_t)h * F_ + f) * D_ + d];
        return;
    }
    int tid = gid - 65536;
    if (tid >= 2 * H_ * FT) return;
    int sel = tid / (H_ * FT);
    int r = tid - sel * (H_ * FT);
    int h = r / FT, f = r - h * FT;
    const float* Wx = sel ? Wk : Wq;
    const float* av = a + h * 2 * D_ + sel * D_;
    const float* wrow = Wx + (size_t)(h * FT + f) * D_;
    float acc = 0.f;
    for (int d = 0; d < D_; ++d) acc += wrow[d] * av[d];
    (sel ? v2 : v1)[h * FT + f] = acc * LOG2E;
}

// K2 (fused mid): blocks [0,2048): e12; [2048, 2560): wht.
__global__ __launch_bounds__(256) void k_mid(const float* __restrict__ x,
                                             const float* __restrict__ oh,
                                             const float* __restrict__ v1,
                                             const float* __restrict__ v2,
                                             const _Float16* __restrict__ WT,
                                             float2* __restrict__ E1A,
                                             float2* __restrict__ E2A,
                                             _Float16* __restrict__ WhT) {
    if (blockIdx.x < 2048u) {
        // ---- e12: per-node factored exponentials (fp32), one wave per (b,n) ----
        int lane = threadIdx.x & 63;
        int w = threadIdx.x >> 6;
        int bn = blockIdx.x * 4 + w;
        int b = bn >> 11, n = bn & (N_ - 1);
        float a1h[H_] = {0.f, 0.f, 0.f, 0.f};
        float a2h[H_] = {0.f, 0.f, 0.f, 0.f};
        const float* xrow = x + (size_t)(b * N_ + n) * F_;
        for (int c = 0; c < 4; ++c) {
            int f = c * 64 + lane;
            float xv = xrow[f];
            #pragma unroll
            for (int h = 0; h < H_; ++h) {
                a1h[h] += xv * v1[h * FT + f];
                a2h[h] += xv * v2[h * FT + f];
            }
        }
        if (lane < T_) {
            float ov = oh[(size_t)(b * N_ + n) * T_ + lane];
            #pragma unroll
            for (int h = 0; h < H_; ++h) {
                a1h[h] += ov * v1[h * FT + F_ + lane];
                a2h[h] += ov * v2[h * FT + F_ + lane];
            }
        }
        #pragma unroll
        for (int off = 32; off; off >>= 1) {
            #pragma unroll
            for (int h = 0; h < H_; ++h) {
                a1h[h] += __shfl_xor(a1h[h], off, 64);
                a2h[h] += __shfl_xor(a2h[h], off, 64);
            }
        }
        if (lane == 0) {
            #pragma unroll
            for (int h = 0; h < H_; ++h) {
                size_t o = (size_t)(b * H_ + h) * N_ + n;
                E1A[o] = {EXP2F(a1h[h]), EXP2F(ALPHA * a1h[h])};
                E2A[o] = {EXP2F(a2h[h]), EXP2F(ALPHA * a2h[h])};
            }
        }
        return;
    }
    // ---- wht: WhT[b][hd][j] = fp16( sum_f x[b,j,f] * W[h,f,d] ) via fp16 MFMA ----
    int bid = blockIdx.x - 2048;
    int jt = bid & 127, b = bid >> 7;
    int lane = threadIdx.x & 63;
    int h = threadIdx.x >> 6;
    int j0 = jt * 16;
    int m = lane & 15, quad = lane >> 4;
    float4v zero = {0.f, 0.f, 0.f, 0.f};
    float4v acc[4] = {zero, zero, zero, zero};
    #pragma unroll 2
    for (int f0 = 0; f0 < F_; f0 += 32) {
        const float* xp = x + (size_t)(b * N_ + j0 + m) * F_ + f0 + quad * 8;
        float4v xlo = *(const float4v*)xp;
        float4v xhi = *(const float4v*)(xp + 4);
        uint4v bp = {pkrtz_u(xlo[0], xlo[1]), pkrtz_u(xlo[2], xlo[3]),
                     pkrtz_u(xhi[0], xhi[1]), pkrtz_u(xhi[2], xhi[3])};
        half8 bfrag = __builtin_bit_cast(half8, bp);
        #pragma unroll
        for (int mt = 0; mt < 4; ++mt) {
            const _Float16* ap = WT + (size_t)(h * 64 + mt * 16 + m) * F_ + f0 + quad * 8;
            half8 afrag = *(const half8*)ap;
            acc[mt] = __builtin_amdgcn_mfma_f32_16x16x32_f16(afrag, bfrag, acc[mt], 0, 0, 0);
        }
    }
    #pragma unroll
    for (int mt = 0; mt < 4; ++mt) {
        #pragma unroll
        for (int reg = 0; reg < 4; ++reg) {
            int hd = h * 64 + mt * 16 + quad * 4 + reg;
            WhT[((size_t)b * 256 + hd) * N_ + j0 + m] = (_Float16)acc[mt][reg];
        }
    }
}

// K3: partial column sums from the L2-resident bitmask. grid (8 jt, 4 b, 16 ic).
__global__ __launch_bounds__(256) void k_colsum(const unsigned* __restrict__ bits,
                                                const float2* __restrict__ E1A,
                                                const float2* __restrict__ E2A,
                                                float* __restrict__ part_s) {
    int tid = threadIdx.x;
    int jt = blockIdx.x, b = blockIdx.y, ic = blockIdx.z;
    int j = jt * 256 + tid;
    int i0 = ic * 128;
    float2 e2v[H_];
    float acc[H_] = {0.f, 0.f, 0.f, 0.f};
    #pragma unroll
    for (int h = 0; h < H_; ++h) e2v[h] = E2A[(size_t)(b * H_ + h) * N_ + j];
    const float2* e1b = E1A + (size_t)(b * H_) * N_;
    const unsigned* bp = bits + ((size_t)(b * N_ + i0)) * 64 + (j >> 5);
    unsigned sh = j & 31;
    #pragma unroll 8
    for (int k = 0; k < 128; ++k) {
        unsigned wv = bp[(size_t)k * 64];
        bool on = (wv >> sh) & 1u;
        int i = i0 + k;
        #pragma unroll
        for (int h = 0; h < H_; ++h) {
            float2 e1 = e1b[h * N_ + i];                 // uniform -> s_load
            float t = fmaxf(e1.x * e2v[h].x, e1.y * e2v[h].y);
            acc[h] += on ? t : 0.f;
        }
    }
    #pragma unroll
    for (int h = 0; h < H_; ++h)
        part_s[(size_t)ic * (B_ * H_ * N_) + (size_t)(b * H_ + h) * N_ + j] = acc[h];
}

// K4: main (with k_scale folded into the LDS prologue). Core loop identical to r8.
__global__ __launch_bounds__(256, 2) void k_main(const unsigned* __restrict__ bits,
                                                 const float2* __restrict__ E1A,
                                                 const float2* __restrict__ E2A,
                                                 const float* __restrict__ parts,
                                                 const _Float16* __restrict__ WhT,
                                                 float* __restrict__ out) {
    __shared__ float sPC[2048];           // 8 KB
    __shared__ float sNC[2048];           // 8 KB
    __shared__ unsigned sLUT[256][4];     // 4 KB : byte -> 4 packed half-masks
    __shared__ _Float16 sW[2][8192];      // 2 x 16 KB : 64 d-rows x 128 j (swizzled)
    int lane = threadIdx.x;   // 64
    int wy = threadIdx.y;     // 4 : i-tile
    int it = blockIdx.x;      // 32
    int b  = blockIdx.y;      // 4
    int h  = blockIdx.z;      // 4
    int ibase = it * 64 + wy * 16;
    int m = lane & 15, quad = lane >> 4;
    int bh = b * H_ + h;
    int t256 = wy * 64 + lane;

    // LUT + fused scale prologue: pc/nc = E2*{1/s} straight into LDS
    {
        unsigned t = t256;
        sLUT[t][0] = ((t & 1u) ? 0xFFFFu : 0u) | ((t & 2u) ? 0xFFFF0000u : 0u);
        sLUT[t][1] = ((t & 4u) ? 0xFFFFu : 0u) | ((t & 8u) ? 0xFFFF0000u : 0u);
        sLUT[t][2] = ((t & 16u) ? 0xFFFFu : 0u) | ((t & 32u) ? 0xFFFF0000u : 0u);
        sLUT[t][3] = ((t & 64u) ? 0xFFFFu : 0u) | ((t & 128u) ? 0xFFFF0000u : 0u);
        int base = t256 * 8;
        float4v s0 = {0.f, 0.f, 0.f, 0.f}, s1 = {0.f, 0.f, 0.f, 0.f};
        #pragma unroll
        for (int ic = 0; ic < 16; ++ic) {
            const float* pp = parts + (size_t)ic * (B_ * H_ * N_) + (size_t)bh * N_ + base;
            s0 += *(const float4v*)pp;
            s1 += *(const float4v*)(pp + 4);
        }
        const float2* e2p = E2A + (size_t)bh * N_ + base;
        #pragma unroll
        for (int e = 0; e < 4; ++e) {
            float s = s0[e];
            float c = (s > 0.f) ? 1.f / s : 0.f;
            float2 e2 = e2p[e];
            sPC[base + e] = e2.x * c;
            sNC[base + e] = e2.y * c;
        }
        #pragma unroll
        for (int e = 0; e < 4; ++e) {
            float s = s1[e];
            float c = (s > 0.f) ? 1.f / s : 0.f;
            float2 e2 = e2p[4 + e];
            sPC[base + 4 + e] = e2.x * c;
            sNC[base + 4 + e] = e2.y * c;
        }
    }
    float2 e1v = E1A[(size_t)bh * N_ + ibase + m];   // {P1, N1} for row i=ibase+m
    const _Float16* bbase = WhT + (size_t)(b * 256 + h * 64) * N_;
    const unsigned* brow = bits + ((size_t)(b * N_) + ibase + m) * 64;

    // stage a 64d x 128j chunk into sW[buf] (16-seg XOR swizzle)
    auto stage = [&](int buf, int jb) {
        #pragma unroll
        for (int q = 0; q < 4; ++q) {
            int r = q * 16 + wy * 4 + (lane >> 4);
            int g = (lane & 15) ^ (r & 15);
            const _Float16* gp = bbase + (size_t)r * N_ + jb + g * 8;
            void* lp = (void*)&sW[buf][q * 2048 + wy * 512];  // wave-uniform base
            gl2lds16(gp, lp);
        }
    };

    stage(0, 0);
    __syncthreads();

    float4v zero = {0.f, 0.f, 0.f, 0.f};
    float4v acc[4] = {zero, zero, zero, zero};

    for (int k = 0; k < 16; ++k) {
        if (k < 15) stage((k + 1) & 1, (k + 1) * 128);
        uint4v bwv = *(const uint4v*)(brow + k * 4);
        #pragma unroll
        for (int u = 0; u < 4; ++u) {
            unsigned byte = (bwv[u] >> (quad * 8)) & 0xFFu;
            uint4v msk = *(const uint4v*)&sLUT[byte][0];
            int jg = k * 128 + u * 32 + quad * 8;
            float4v p0 = *(const float4v*)&sPC[jg];
            float4v p1 = *(const float4v*)&sPC[jg + 4];
            float4v n0 = *(const float4v*)&sNC[jg];
            float4v n1 = *(const float4v*)&sNC[jg + 4];
            float w[8];
            #pragma unroll
            for (int e = 0; e < 4; ++e) w[e]     = fmaxf(e1v.x * p0[e], e1v.y * n0[e]);
            #pragma unroll
            for (int e = 0; e < 4; ++e) w[4 + e] = fmaxf(e1v.x * p1[e], e1v.y * n1[e]);
            uint4v wvp = {pkrtz_u(w[0], w[1]) & msk[0], pkrtz_u(w[2], w[3]) & msk[1],
                          pkrtz_u(w[4], w[5]) & msk[2], pkrtz_u(w[6], w[7]) & msk[3]};
            half8 afrag = __builtin_bit_cast(half8, wvp);
            #pragma unroll
            for (int dt = 0; dt < 4; ++dt) {
                int r = dt * 16 + m;
                int segp = (u * 4 + quad) ^ m;       // r & 15 == m
                half8 bfrag = *(const half8*)&sW[k & 1][r * 128 + segp * 8];
                acc[dt] = __builtin_amdgcn_mfma_f32_16x16x32_f16(afrag, bfrag, acc[dt], 0, 0, 0);
            }
        }
        __syncthreads();
    }

    #pragma unroll
    for (int dt = 0; dt < 4; ++dt) {
        #pragma unroll
        for (int reg = 0; reg < 4; ++reg) {
            int i = ibase + quad * 4 + reg;
            int d = dt * 16 + m;
            float v = acc[dt][reg];
            v = v > 0.f ? v : expm1f(v);  // ELU
            out[((size_t)(b * N_ + i)) * (H_ * D_) + h * D_ + d] = v;
        }
    }
}

extern "C" void kernel_launch(void* const* d_in, const int* in_sizes, int n_in,
                              void* d_out, int out_size, void* d_ws, size_t ws_size,
                              hipStream_t stream) {
    const float* x   = (const float*)d_in[0];
    const int*   adj = (const int*)d_in[1];
    const float* oh  = (const float*)d_in[2];
    const float* Wq  = (const float*)d_in[3];
    const float* Wk  = (const float*)d_in[4];
    const float* W   = (const float*)d_in[5];
    const float* a   = (const float*)d_in[6];
    float* out = (float*)d_out;
    char* ws = (char*)d_ws;

    float*   v1    = (float*)(ws + V1_OFF);
    float*   v2    = (float*)(ws + V2_OFF);
    float2*  E1A   = (float2*)(ws + E1A_OFF);
    float2*  E2A   = (float2*)(ws + E2A_OFF);
    float*   parts = (float*)(ws + PARTS_OFF);
    _Float16* WT   = (_Float16*)(ws + WT_OFF);
    unsigned* bits = (unsigned*)(ws + BITS_OFF);
    _Float16* WhT  = (_Float16*)(ws + WHT_OFF);

    k_pre<<<65536 + 265, 256, 0, stream>>>(adj, Wq, Wk, a, W, bits, v1, v2, WT);
    k_mid<<<2048 + 512, 256, 0, stream>>>(x, oh, v1, v2, WT, E1A, E2A, WhT);
    k_colsum<<<dim3(8, 4, 16), 256, 0, stream>>>(bits, E1A, E2A, parts);
    k_main<<<dim3(32, 4, 4), dim3(64, 4), 0, stream>>>(bits, E1A, E2A, parts, WhT, out);
}

// Round 10
// 180.440 us; speedup vs baseline: 1.0385x; 1.0385x over previous
//
#include <hip/hip_runtime.h>
#include <hip/hip_bf16.h>
#include <math.h>

#define ALPHA 0.2f
#define LOG2E 1.4426950408889634f

constexpr int B_ = 4, N_ = 2048, F_ = 256, T_ = 8, H_ = 4, D_ = 64;
constexpr int FT = F_ + T_; // 264

using half8   = __attribute__((ext_vector_type(8))) _Float16;
using float4v = __attribute__((ext_vector_type(4))) float;
using int4v   = __attribute__((ext_vector_type(4))) int;
using uint4v  = __attribute__((ext_vector_type(4))) unsigned;

#if __has_builtin(__builtin_amdgcn_exp2f)
#define EXP2F(x) __builtin_amdgcn_exp2f(x)
#else
#define EXP2F(x) exp2f(x)
#endif

__device__ inline unsigned pkrtz_u(float a, float b) {
    return __builtin_bit_cast(unsigned, __builtin_amdgcn_cvt_pkrtz(a, b));
}

// ---- workspace byte offsets (16B aligned; same as r8/r9 passing layout) ----
#define V1_OFF    0u          // 4*264 f32
#define V2_OFF    4224u       // 4*264 f32
#define E1A_OFF   8448u       // [b][h][n] float2 {P1,N1} fp32        (256 KB)
#define E2A_OFF   270592u     // [b][h][n] float2 {P2,N2} fp32        (256 KB)
#define PARTS_OFF 794880u     // 16 x [b][h][n] f32 partial colsums   (2 MB)
#define WT_OFF    2892032u    // 256*256 fp16 : W^T [hd][f]           (128 KB)
#define BITS_OFF  3023104u    // [b][i][64 words] adj bitmask         (2 MB)
#define WHT_OFF   5120256u    // [b][hd][j] fp16 Wh^T                 (4 MB)

__device__ inline void gl2lds16(const void* g, void* l) {
    __builtin_amdgcn_global_load_lds(
        (const __attribute__((address_space(1))) unsigned*)g,
        (__attribute__((address_space(3))) unsigned*)l, 16, 0, 0);
}

// K1 (fused pre): blocks [0,16384): adjpack (int4 + nibble/shfl pack);
//                 [16384, 16384+265): WT cast + v1/v2.
__global__ __launch_bounds__(256) void k_pre(const int* __restrict__ adj,
                                             const float* __restrict__ Wq,
                                             const float* __restrict__ Wk,
                                             const float* __restrict__ a,
                                             const float* __restrict__ W,
                                             unsigned* __restrict__ bits,
                                             float* __restrict__ v1,
                                             float* __restrict__ v2,
                                             _Float16* __restrict__ WT) {
    if (blockIdx.x < 16384u) {
        size_t t = (size_t)blockIdx.x * 256 + threadIdx.x;  // 4,194,304 threads
        int lane = threadIdx.x & 63;
        int4v av = ((const int4v*)adj)[t];
        unsigned nib = (av.x != 0 ? 1u : 0u) | (av.y != 0 ? 2u : 0u) |
                       (av.z != 0 ? 4u : 0u) | (av.w != 0 ? 8u : 0u);
        unsigned v = nib << ((lane & 7) * 4);
        v |= __shfl_xor(v, 1, 64);
        v |= __shfl_xor(v, 2, 64);
        v |= __shfl_xor(v, 4, 64);
        if ((lane & 7) == 0) bits[t >> 3] = v;
        return;
    }
    int gid = (blockIdx.x - 16384) * 256 + threadIdx.x;
    if (gid < 65536) {
        int hd = gid >> 8, f = gid & 255;
        int h = hd >> 6, d = hd & 63;
        WT[(size_t)hd * F_ + f] = (_Float16)W[((size_t)h * F_ + f) * D_ + d];
        return;
    }
    int tid = gid - 65536;
    if (tid >= 2 * H_ * FT) return;
    int sel = tid / (H_ * FT);
    int r = tid - sel * (H_ * FT);
    int h = r / FT, f = r - h * FT;
    const float* Wx = sel ? Wk : Wq;
    const float* av = a + h * 2 * D_ + sel * D_;
    const float* wrow = Wx + (size_t)(h * FT + f) * D_;
    float acc = 0.f;
    for (int d = 0; d < D_; ++d) acc += wrow[d] * av[d];
    (sel ? v2 : v1)[h * FT + f] = acc * LOG2E;
}

// K2 (fused mid): blocks [0,2048): e12; [2048, 2560): wht.   (unchanged from r9)
__global__ __launch_bounds__(256) void k_mid(const float* __restrict__ x,
                                             const float* __restrict__ oh,
                                             const float* __restrict__ v1,
                                             const float* __restrict__ v2,
                                             const _Float16* __restrict__ WT,
                                             float2* __restrict__ E1A,
                                             float2* __restrict__ E2A,
                                             _Float16* __restrict__ WhT) {
    if (blockIdx.x < 2048u) {
        int lane = threadIdx.x & 63;
        int w = threadIdx.x >> 6;
        int bn = blockIdx.x * 4 + w;
        int b = bn >> 11, n = bn & (N_ - 1);
        float a1h[H_] = {0.f, 0.f, 0.f, 0.f};
        float a2h[H_] = {0.f, 0.f, 0.f, 0.f};
        const float* xrow = x + (size_t)(b * N_ + n) * F_;
        for (int c = 0; c < 4; ++c) {
            int f = c * 64 + lane;
            float xv = xrow[f];
            #pragma unroll
            for (int h = 0; h < H_; ++h) {
                a1h[h] += xv * v1[h * FT + f];
                a2h[h] += xv * v2[h * FT + f];
            }
        }
        if (lane < T_) {
            float ov = oh[(size_t)(b * N_ + n) * T_ + lane];
            #pragma unroll
            for (int h = 0; h < H_; ++h) {
                a1h[h] += ov * v1[h * FT + F_ + lane];
                a2h[h] += ov * v2[h * FT + F_ + lane];
            }
        }
        #pragma unroll
        for (int off = 32; off; off >>= 1) {
            #pragma unroll
            for (int h = 0; h < H_; ++h) {
                a1h[h] += __shfl_xor(a1h[h], off, 64);
                a2h[h] += __shfl_xor(a2h[h], off, 64);
            }
        }
        if (lane == 0) {
            #pragma unroll
            for (int h = 0; h < H_; ++h) {
                size_t o = (size_t)(b * H_ + h) * N_ + n;
                E1A[o] = {EXP2F(a1h[h]), EXP2F(ALPHA * a1h[h])};
                E2A[o] = {EXP2F(a2h[h]), EXP2F(ALPHA * a2h[h])};
            }
        }
        return;
    }
    int bid = blockIdx.x - 2048;
    int jt = bid & 127, b = bid >> 7;
    int lane = threadIdx.x & 63;
    int h = threadIdx.x >> 6;
    int j0 = jt * 16;
    int m = lane & 15, quad = lane >> 4;
    float4v zero = {0.f, 0.f, 0.f, 0.f};
    float4v acc[4] = {zero, zero, zero, zero};
    #pragma unroll 2
    for (int f0 = 0; f0 < F_; f0 += 32) {
        const float* xp = x + (size_t)(b * N_ + j0 + m) * F_ + f0 + quad * 8;
        float4v xlo = *(const float4v*)xp;
        float4v xhi = *(const float4v*)(xp + 4);
        uint4v bp = {pkrtz_u(xlo[0], xlo[1]), pkrtz_u(xlo[2], xlo[3]),
                     pkrtz_u(xhi[0], xhi[1]), pkrtz_u(xhi[2], xhi[3])};
        half8 bfrag = __builtin_bit_cast(half8, bp);
        #pragma unroll
        for (int mt = 0; mt < 4; ++mt) {
            const _Float16* ap = WT + (size_t)(h * 64 + mt * 16 + m) * F_ + f0 + quad * 8;
            half8 afrag = *(const half8*)ap;
            acc[mt] = __builtin_amdgcn_mfma_f32_16x16x32_f16(afrag, bfrag, acc[mt], 0, 0, 0);
        }
    }
    #pragma unroll
    for (int mt = 0; mt < 4; ++mt) {
        #pragma unroll
        for (int reg = 0; reg < 4; ++reg) {
            int hd = h * 64 + mt * 16 + quad * 4 + reg;
            WhT[((size_t)b * 256 + hd) * N_ + j0 + m] = (_Float16)acc[mt][reg];
        }
    }
}

// K3: partial column sums. e1 chunk staged in LDS (kills serialized s_loads).
// grid (8 jt, 4 b, 16 ic of 128 i), block 256.
__global__ __launch_bounds__(256) void k_colsum(const unsigned* __restrict__ bits,
                                                const float2* __restrict__ E1A,
                                                const float2* __restrict__ E2A,
                                                float* __restrict__ part_s) {
    __shared__ float2 sE1[H_][128];   // 4 KB
    int tid = threadIdx.x;
    int jt = blockIdx.x, b = blockIdx.y, ic = blockIdx.z;
    int j = jt * 256 + tid;
    int i0 = ic * 128;
    // stage e1 for this i-chunk: 512 float2 by 256 threads
    #pragma unroll
    for (int r = 0; r < 2; ++r) {
        int idx = r * 256 + tid;          // 0..511
        int hh = idx >> 7, ii = idx & 127;
        sE1[hh][ii] = E1A[(size_t)(b * H_ + hh) * N_ + i0 + ii];
    }
    float2 e2v[H_];
    float acc[H_] = {0.f, 0.f, 0.f, 0.f};
    #pragma unroll
    for (int h = 0; h < H_; ++h) e2v[h] = E2A[(size_t)(b * H_ + h) * N_ + j];
    __syncthreads();
    const unsigned* bp = bits + ((size_t)(b * N_ + i0)) * 64 + (j >> 5);
    unsigned sh = j & 31;
    #pragma unroll 8
    for (int k = 0; k < 128; ++k) {
        unsigned wv = bp[(size_t)k * 64];
        bool on = (wv >> sh) & 1u;
        #pragma unroll
        for (int h = 0; h < H_; ++h) {
            float2 e1 = sE1[h][k];        // block-uniform -> LDS broadcast
            float t = fmaxf(e1.x * e2v[h].x, e1.y * e2v[h].y);
            acc[h] += on ? t : 0.f;
        }
    }
    #pragma unroll
    for (int h = 0; h < H_; ++h)
        part_s[(size_t)ic * (B_ * H_ * N_) + (size_t)(b * H_ + h) * N_ + j] = acc[h];
}

// K4: main. Block covers 128 i (2 i-tiles per wave -> bfrag/pcnc LDS traffic
// halved per unit work); VALU selects instead of LUT (no bank conflicts).
// grid (16 it, 4 b, 4 h), block (64,4). Scale folded in prologue.
__global__ __launch_bounds__(256, 2) void k_main(const unsigned* __restrict__ bits,
                                                 const float2* __restrict__ E1A,
                                                 const float2* __restrict__ E2A,
                                                 const float* __restrict__ parts,
                                                 const _Float16* __restrict__ WhT,
                                                 float* __restrict__ out) {
    __shared__ float sPC[2048];           // 8 KB
    __shared__ float sNC[2048];           // 8 KB
    __shared__ _Float16 sW[2][8192];      // 2 x 16 KB : 64 d-rows x 128 j (swizzled)
    int lane = threadIdx.x;   // 64
    int wy = threadIdx.y;     // 4 : i-pair-tile
    int it = blockIdx.x;      // 16
    int b  = blockIdx.y;      // 4
    int h  = blockIdx.z;      // 4
    int ibase = it * 128 + wy * 32;       // wave: i in [ibase, ibase+32)
    int m = lane & 15, quad = lane >> 4;
    int bh = b * H_ + h;
    int t256 = wy * 64 + lane;

    // fused scale prologue: pc/nc = E2*{1/s} straight into LDS
    {
        int base = t256 * 8;
        float4v s0 = {0.f, 0.f, 0.f, 0.f}, s1 = {0.f, 0.f, 0.f, 0.f};
        #pragma unroll
        for (int ic = 0; ic < 16; ++ic) {
            const float* pp = parts + (size_t)ic * (B_ * H_ * N_) + (size_t)bh * N_ + base;
            s0 += *(const float4v*)pp;
            s1 += *(const float4v*)(pp + 4);
        }
        const float2* e2p = E2A + (size_t)bh * N_ + base;
        #pragma unroll
        for (int e = 0; e < 4; ++e) {
            float s = s0[e];
            float c = (s > 0.f) ? 1.f / s : 0.f;
            float2 e2 = e2p[e];
            sPC[base + e] = e2.x * c;
            sNC[base + e] = e2.y * c;
        }
        #pragma unroll
        for (int e = 0; e < 4; ++e) {
            float s = s1[e];
            float c = (s > 0.f) ? 1.f / s : 0.f;
            float2 e2 = e2p[4 + e];
            sPC[base + 4 + e] = e2.x * c;
            sNC[base + 4 + e] = e2.y * c;
        }
    }
    float2 e1vA = E1A[(size_t)bh * N_ + ibase + m];
    float2 e1vB = E1A[(size_t)bh * N_ + ibase + 16 + m];
    const _Float16* bbase = WhT + (size_t)(b * 256 + h * 64) * N_;
    const unsigned* browA = bits + ((size_t)(b * N_) + ibase + m) * 64;
    const unsigned* browB = bits + ((size_t)(b * N_) + ibase + 16 + m) * 64;

    // stage a 64d x 128j chunk into sW[buf] (16-seg XOR swizzle)
    auto stage = [&](int buf, int jb) {
        #pragma unroll
        for (int q = 0; q < 4; ++q) {
            int r = q * 16 + wy * 4 + (lane >> 4);
            int g = (lane & 15) ^ (r & 15);
            const _Float16* gp = bbase + (size_t)r * N_ + jb + g * 8;
            void* lp = (void*)&sW[buf][q * 2048 + wy * 512];  // wave-uniform base
            gl2lds16(gp, lp);
        }
    };

    stage(0, 0);
    __syncthreads();

    float4v zero = {0.f, 0.f, 0.f, 0.f};
    float4v accA[4] = {zero, zero, zero, zero};
    float4v accB[4] = {zero, zero, zero, zero};

    for (int k = 0; k < 16; ++k) {
        if (k < 15) stage((k + 1) & 1, (k + 1) * 128);
        uint4v bwA = *(const uint4v*)(browA + k * 4);
        uint4v bwB = *(const uint4v*)(browB + k * 4);
        #pragma unroll
        for (int u = 0; u < 4; ++u) {
            unsigned wqA = bwA[u] >> (quad * 8);
            unsigned wqB = bwB[u] >> (quad * 8);
            int jg = k * 128 + u * 32 + quad * 8;
            float4v p0 = *(const float4v*)&sPC[jg];
            float4v p1 = *(const float4v*)&sPC[jg + 4];
            float4v n0 = *(const float4v*)&sNC[jg];
            float4v n1 = *(const float4v*)&sNC[jg + 4];
            float wA[8], wB[8];
            #pragma unroll
            for (int e = 0; e < 4; ++e) {
                float tA0 = fmaxf(e1vA.x * p0[e], e1vA.y * n0[e]);
                float tA1 = fmaxf(e1vA.x * p1[e], e1vA.y * n1[e]);
                wA[e]     = (wqA & (1u << e))  ? tA0 : 0.f;
                wA[4 + e] = (wqA & (16u << e)) ? tA1 : 0.f;
                float tB0 = fmaxf(e1vB.x * p0[e], e1vB.y * n0[e]);
                float tB1 = fmaxf(e1vB.x * p1[e], e1vB.y * n1[e]);
                wB[e]     = (wqB & (1u << e))  ? tB0 : 0.f;
                wB[4 + e] = (wqB & (16u << e)) ? tB1 : 0.f;
            }
            uint4v wpA = {pkrtz_u(wA[0], wA[1]), pkrtz_u(wA[2], wA[3]),
                          pkrtz_u(wA[4], wA[5]), pkrtz_u(wA[6], wA[7])};
            uint4v wpB = {pkrtz_u(wB[0], wB[1]), pkrtz_u(wB[2], wB[3]),
                          pkrtz_u(wB[4], wB[5]), pkrtz_u(wB[6], wB[7])};
            half8 afA = __builtin_bit_cast(half8, wpA);
            half8 afB = __builtin_bit_cast(half8, wpB);
            #pragma unroll
            for (int dt = 0; dt < 4; ++dt) {
                int r = dt * 16 + m;
                int segp = (u * 4 + quad) ^ m;       // r & 15 == m
                half8 bfrag = *(const half8*)&sW[k & 1][r * 128 + segp * 8];
                accA[dt] = __builtin_amdgcn_mfma_f32_16x16x32_f16(afA, bfrag, accA[dt], 0, 0, 0);
                accB[dt] = __builtin_amdgcn_mfma_f32_16x16x32_f16(afB, bfrag, accB[dt], 0, 0, 0);
            }
        }
        __syncthreads();
    }

    #pragma unroll
    for (int dt = 0; dt < 4; ++dt) {
        #pragma unroll
        for (int reg = 0; reg < 4; ++reg) {
            int iA = ibase + quad * 4 + reg;
            int d = dt * 16 + m;
            float vA = accA[dt][reg];
            vA = vA > 0.f ? vA : expm1f(vA);  // ELU
            out[((size_t)(b * N_ + iA)) * (H_ * D_) + h * D_ + d] = vA;
            float vB = accB[dt][reg];
            vB = vB > 0.f ? vB : expm1f(vB);
            out[((size_t)(b * N_ + iA + 16)) * (H_ * D_) + h * D_ + d] = vB;
        }
    }
}

extern "C" void kernel_launch(void* const* d_in, const int* in_sizes, int n_in,
                              void* d_out, int out_size, void* d_ws, size_t ws_size,
                              hipStream_t stream) {
    const float* x   = (const float*)d_in[0];
    const int*   adj = (const int*)d_in[1];
    const float* oh  = (const float*)d_in[2];
    const float* Wq  = (const float*)d_in[3];
    const float* Wk  = (const float*)d_in[4];
    const float* W   = (const float*)d_in[5];
    const float* a   = (const float*)d_in[6];
    float* out = (float*)d_out;
    char* ws = (char*)d_ws;

    float*   v1    = (float*)(ws + V1_OFF);
    float*   v2    = (float*)(ws + V2_OFF);
    float2*  E1A   = (float2*)(ws + E1A_OFF);
    float2*  E2A   = (float2*)(ws + E2A_OFF);
    float*   parts = (float*)(ws + PARTS_OFF);
    _Float16* WT   = (_Float16*)(ws + WT_OFF);
    unsigned* bits = (unsigned*)(ws + BITS_OFF);
    _Float16* WhT  = (_Float16*)(ws + WHT_OFF);

    k_pre<<<16384 + 265, 256, 0, stream>>>(adj, Wq, Wk, a, W, bits, v1, v2, WT);
    k_mid<<<2048 + 512, 256, 0, stream>>>(x, oh, v1, v2, WT, E1A, E2A, WhT);
    k_colsum<<<dim3(8, 4, 16), 256, 0, stream>>>(bits, E1A, E2A, parts);
    k_main<<<dim3(16, 4, 4), dim3(64, 4), 0, stream>>>(bits, E1A, E2A, parts, WhT, out);
}

// Round 11
// 171.789 us; speedup vs baseline: 1.0908x; 1.0504x over previous
//
#include <hip/hip_runtime.h>
#include <hip/hip_bf16.h>
#include <math.h>

#define ALPHA 0.2f
#define LOG2E 1.4426950408889634f

constexpr int B_ = 4, N_ = 2048, F_ = 256, T_ = 8, H_ = 4, D_ = 64;
constexpr int FT = F_ + T_; // 264

using half8   = __attribute__((ext_vector_type(8))) _Float16;
using float4v = __attribute__((ext_vector_type(4))) float;
using int4v   = __attribute__((ext_vector_type(4))) int;
using uint4v  = __attribute__((ext_vector_type(4))) unsigned;

#if __has_builtin(__builtin_amdgcn_exp2f)
#define EXP2F(x) __builtin_amdgcn_exp2f(x)
#else
#define EXP2F(x) exp2f(x)
#endif

__device__ inline unsigned pkrtz_u(float a, float b) {
    return __builtin_bit_cast(unsigned, __builtin_amdgcn_cvt_pkrtz(a, b));
}

// ---- workspace byte offsets (16B aligned; same as r8-r10 passing layout) ----
#define V1_OFF    0u          // 4*264 f32
#define V2_OFF    4224u       // 4*264 f32
#define E1A_OFF   8448u       // [b][h][n] float2 {P1,N1} fp32        (256 KB)
#define E2A_OFF   270592u     // [b][h][n] float2 {P2,N2} fp32        (256 KB)
#define PARTS_OFF 794880u     // 16 x [b][h][n] f32 partial colsums   (2 MB)
#define WT_OFF    2892032u    // 256*256 fp16 : W^T [hd][f]           (128 KB)
#define BITS_OFF  3023104u    // [b][i][64 words] adj bitmask         (2 MB)
#define WHT_OFF   5120256u    // [b][hd][j] fp16 Wh^T                 (4 MB)

__device__ inline void gl2lds16(const void* g, void* l) {
    __builtin_amdgcn_global_load_lds(
        (const __attribute__((address_space(1))) unsigned*)g,
        (__attribute__((address_space(3))) unsigned*)l, 16, 0, 0);
}

// K1 (fused pre): blocks [0,16384): adjpack (int4 + nibble/shfl pack);
//                 [16384, 16384+265): WT cast + v1/v2.
__global__ __launch_bounds__(256) void k_pre(const int* __restrict__ adj,
                                             const float* __restrict__ Wq,
                                             const float* __restrict__ Wk,
                                             const float* __restrict__ a,
                                             const float* __restrict__ W,
                                             unsigned* __restrict__ bits,
                                             float* __restrict__ v1,
                                             float* __restrict__ v2,
                                             _Float16* __restrict__ WT) {
    if (blockIdx.x < 16384u) {
        size_t t = (size_t)blockIdx.x * 256 + threadIdx.x;  // 4,194,304 threads
        int lane = threadIdx.x & 63;
        int4v av = ((const int4v*)adj)[t];
        unsigned nib = (av.x != 0 ? 1u : 0u) | (av.y != 0 ? 2u : 0u) |
                       (av.z != 0 ? 4u : 0u) | (av.w != 0 ? 8u : 0u);
        unsigned v = nib << ((lane & 7) * 4);
        v |= __shfl_xor(v, 1, 64);
        v |= __shfl_xor(v, 2, 64);
        v |= __shfl_xor(v, 4, 64);
        if ((lane & 7) == 0) bits[t >> 3] = v;
        return;
    }
    int gid = (blockIdx.x - 16384) * 256 + threadIdx.x;
    if (gid < 65536) {
        int hd = gid >> 8, f = gid & 255;
        int h = hd >> 6, d = hd & 63;
        WT[(size_t)hd * F_ + f] = (_Float16)W[((size_t)h * F_ + f) * D_ + d];
        return;
    }
    int tid = gid - 65536;
    if (tid >= 2 * H_ * FT) return;
    int sel = tid / (H_ * FT);
    int r = tid - sel * (H_ * FT);
    int h = r / FT, f = r - h * FT;
    const float* Wx = sel ? Wk : Wq;
    const float* av = a + h * 2 * D_ + sel * D_;
    const float* wrow = Wx + (size_t)(h * FT + f) * D_;
    float acc = 0.f;
    for (int d = 0; d < D_; ++d) acc += wrow[d] * av[d];
    (sel ? v2 : v1)[h * FT + f] = acc * LOG2E;
}

// K2 (fused mid): blocks [0,2048): e12; [2048, 2560): wht.
__global__ __launch_bounds__(256) void k_mid(const float* __restrict__ x,
                                             const float* __restrict__ oh,
                                             const float* __restrict__ v1,
                                             const float* __restrict__ v2,
                                             const _Float16* __restrict__ WT,
                                             float2* __restrict__ E1A,
                                             float2* __restrict__ E2A,
                                             _Float16* __restrict__ WhT) {
    if (blockIdx.x < 2048u) {
        int lane = threadIdx.x & 63;
        int w = threadIdx.x >> 6;
        int bn = blockIdx.x * 4 + w;
        int b = bn >> 11, n = bn & (N_ - 1);
        float a1h[H_] = {0.f, 0.f, 0.f, 0.f};
        float a2h[H_] = {0.f, 0.f, 0.f, 0.f};
        const float* xrow = x + (size_t)(b * N_ + n) * F_;
        for (int c = 0; c < 4; ++c) {
            int f = c * 64 + lane;
            float xv = xrow[f];
            #pragma unroll
            for (int h = 0; h < H_; ++h) {
                a1h[h] += xv * v1[h * FT + f];
                a2h[h] += xv * v2[h * FT + f];
            }
        }
        if (lane < T_) {
            float ov = oh[(size_t)(b * N_ + n) * T_ + lane];
            #pragma unroll
            for (int h = 0; h < H_; ++h) {
                a1h[h] += ov * v1[h * FT + F_ + lane];
                a2h[h] += ov * v2[h * FT + F_ + lane];
            }
        }
        #pragma unroll
        for (int off = 32; off; off >>= 1) {
            #pragma unroll
            for (int h = 0; h < H_; ++h) {
                a1h[h] += __shfl_xor(a1h[h], off, 64);
                a2h[h] += __shfl_xor(a2h[h], off, 64);
            }
        }
        if (lane == 0) {
            #pragma unroll
            for (int h = 0; h < H_; ++h) {
                size_t o = (size_t)(b * H_ + h) * N_ + n;
                E1A[o] = {EXP2F(a1h[h]), EXP2F(ALPHA * a1h[h])};
                E2A[o] = {EXP2F(a2h[h]), EXP2F(ALPHA * a2h[h])};
            }
        }
        return;
    }
    int bid = blockIdx.x - 2048;
    int jt = bid & 127, b = bid >> 7;
    int lane = threadIdx.x & 63;
    int h = threadIdx.x >> 6;
    int j0 = jt * 16;
    int m = lane & 15, quad = lane >> 4;
    float4v zero = {0.f, 0.f, 0.f, 0.f};
    float4v acc[4] = {zero, zero, zero, zero};
    #pragma unroll 2
    for (int f0 = 0; f0 < F_; f0 += 32) {
        const float* xp = x + (size_t)(b * N_ + j0 + m) * F_ + f0 + quad * 8;
        float4v xlo = *(const float4v*)xp;
        float4v xhi = *(const float4v*)(xp + 4);
        uint4v bp = {pkrtz_u(xlo[0], xlo[1]), pkrtz_u(xlo[2], xlo[3]),
                     pkrtz_u(xhi[0], xhi[1]), pkrtz_u(xhi[2], xhi[3])};
        half8 bfrag = __builtin_bit_cast(half8, bp);
        #pragma unroll
        for (int mt = 0; mt < 4; ++mt) {
            const _Float16* ap = WT + (size_t)(h * 64 + mt * 16 + m) * F_ + f0 + quad * 8;
            half8 afrag = *(const half8*)ap;
            acc[mt] = __builtin_amdgcn_mfma_f32_16x16x32_f16(afrag, bfrag, acc[mt], 0, 0, 0);
        }
    }
    #pragma unroll
    for (int mt = 0; mt < 4; ++mt) {
        #pragma unroll
        for (int reg = 0; reg < 4; ++reg) {
            int hd = h * 64 + mt * 16 + quad * 4 + reg;
            WhT[((size_t)b * 256 + hd) * N_ + j0 + m] = (_Float16)acc[mt][reg];
        }
    }
}

// K3: partial column sums. e1 chunk staged in LDS. grid (8 jt, 4 b, 16 ic).
__global__ __launch_bounds__(256) void k_colsum(const unsigned* __restrict__ bits,
                                                const float2* __restrict__ E1A,
                                                const float2* __restrict__ E2A,
                                                float* __restrict__ part_s) {
    __shared__ float2 sE1[H_][128];   // 4 KB
    int tid = threadIdx.x;
    int jt = blockIdx.x, b = blockIdx.y, ic = blockIdx.z;
    int j = jt * 256 + tid;
    int i0 = ic * 128;
    #pragma unroll
    for (int r = 0; r < 2; ++r) {
        int idx = r * 256 + tid;          // 0..511
        int hh = idx >> 7, ii = idx & 127;
        sE1[hh][ii] = E1A[(size_t)(b * H_ + hh) * N_ + i0 + ii];
    }
    float2 e2v[H_];
    float acc[H_] = {0.f, 0.f, 0.f, 0.f};
    #pragma unroll
    for (int h = 0; h < H_; ++h) e2v[h] = E2A[(size_t)(b * H_ + h) * N_ + j];
    __syncthreads();
    const unsigned* bp = bits + ((size_t)(b * N_ + i0)) * 64 + (j >> 5);
    unsigned sh = j & 31;
    #pragma unroll 8
    for (int k = 0; k < 128; ++k) {
        unsigned wv = bp[(size_t)k * 64];
        bool on = (wv >> sh) & 1u;
        #pragma unroll
        for (int h = 0; h < H_; ++h) {
            float2 e1 = sE1[h][k];        // block-uniform -> LDS broadcast
            float t = fmaxf(e1.x * e2v[h].x, e1.y * e2v[h].y);
            acc[h] += on ? t : 0.f;
        }
    }
    #pragma unroll
    for (int h = 0; h < H_; ++h)
        part_s[(size_t)ic * (B_ * H_ * N_) + (size_t)(b * H_ + h) * N_ + j] = acc[h];
}

// K4: main — r9 wave mapping (1 i-tile/wave, 512 blocks = 2/CU) + VALU select
// (no LUT -> no bank conflicts). Scale folded in prologue. grid (32,4,4), block (64,4).
__global__ __launch_bounds__(256, 2) void k_main(const unsigned* __restrict__ bits,
                                                 const float2* __restrict__ E1A,
                                                 const float2* __restrict__ E2A,
                                                 const float* __restrict__ parts,
                                                 const _Float16* __restrict__ WhT,
                                                 float* __restrict__ out) {
    __shared__ float sPC[2048];           // 8 KB
    __shared__ float sNC[2048];           // 8 KB
    __shared__ _Float16 sW[2][8192];      // 2 x 16 KB : 64 d-rows x 128 j (swizzled)
    int lane = threadIdx.x;   // 64
    int wy = threadIdx.y;     // 4 : i-tile
    int it = blockIdx.x;      // 32
    int b  = blockIdx.y;      // 4
    int h  = blockIdx.z;      // 4
    int ibase = it * 64 + wy * 16;
    int m = lane & 15, quad = lane >> 4;
    int bh = b * H_ + h;
    int t256 = wy * 64 + lane;

    // fused scale prologue: pc/nc = E2*{1/s} straight into LDS
    {
        int base = t256 * 8;
        float4v s0 = {0.f, 0.f, 0.f, 0.f}, s1 = {0.f, 0.f, 0.f, 0.f};
        #pragma unroll
        for (int ic = 0; ic < 16; ++ic) {
            const float* pp = parts + (size_t)ic * (B_ * H_ * N_) + (size_t)bh * N_ + base;
            s0 += *(const float4v*)pp;
            s1 += *(const float4v*)(pp + 4);
        }
        const float2* e2p = E2A + (size_t)bh * N_ + base;
        #pragma unroll
        for (int e = 0; e < 4; ++e) {
            float s = s0[e];
            float c = (s > 0.f) ? 1.f / s : 0.f;
            float2 e2 = e2p[e];
            sPC[base + e] = e2.x * c;
            sNC[base + e] = e2.y * c;
        }
        #pragma unroll
        for (int e = 0; e < 4; ++e) {
            float s = s1[e];
            float c = (s > 0.f) ? 1.f / s : 0.f;
            float2 e2 = e2p[4 + e];
            sPC[base + 4 + e] = e2.x * c;
            sNC[base + 4 + e] = e2.y * c;
        }
    }
    float2 e1v = E1A[(size_t)bh * N_ + ibase + m];
    const _Float16* bbase = WhT + (size_t)(b * 256 + h * 64) * N_;
    const unsigned* brow = bits + ((size_t)(b * N_) + ibase + m) * 64;

    // stage a 64d x 128j chunk into sW[buf] (16-seg XOR swizzle)
    auto stage = [&](int buf, int jb) {
        #pragma unroll
        for (int q = 0; q < 4; ++q) {
            int r = q * 16 + wy * 4 + (lane >> 4);
            int g = (lane & 15) ^ (r & 15);
            const _Float16* gp = bbase + (size_t)r * N_ + jb + g * 8;
            void* lp = (void*)&sW[buf][q * 2048 + wy * 512];  // wave-uniform base
            gl2lds16(gp, lp);
        }
    };

    stage(0, 0);
    __syncthreads();

    float4v zero = {0.f, 0.f, 0.f, 0.f};
    float4v acc[4] = {zero, zero, zero, zero};

    for (int k = 0; k < 16; ++k) {
        if (k < 15) stage((k + 1) & 1, (k + 1) * 128);
        uint4v bwv = *(const uint4v*)(brow + k * 4);
        #pragma unroll
        for (int u = 0; u < 4; ++u) {
            unsigned wq = bwv[u] >> (quad * 8);
            int jg = k * 128 + u * 32 + quad * 8;
            float4v p0 = *(const float4v*)&sPC[jg];
            float4v p1 = *(const float4v*)&sPC[jg + 4];
            float4v n0 = *(const float4v*)&sNC[jg];
            float4v n1 = *(const float4v*)&sNC[jg + 4];
            float w[8];
            #pragma unroll
            for (int e = 0; e < 4; ++e) {
                float t0 = fmaxf(e1v.x * p0[e], e1v.y * n0[e]);
                float t1 = fmaxf(e1v.x * p1[e], e1v.y * n1[e]);
                w[e]     = (wq & (1u << e))  ? t0 : 0.f;
                w[4 + e] = (wq & (16u << e)) ? t1 : 0.f;
            }
            uint4v wvp = {pkrtz_u(w[0], w[1]), pkrtz_u(w[2], w[3]),
                          pkrtz_u(w[4], w[5]), pkrtz_u(w[6], w[7])};
            half8 afrag = __builtin_bit_cast(half8, wvp);
            #pragma unroll
            for (int dt = 0; dt < 4; ++dt) {
                int r = dt * 16 + m;
                int segp = (u * 4 + quad) ^ m;       // r & 15 == m
                half8 bfrag = *(const half8*)&sW[k & 1][r * 128 + segp * 8];
                acc[dt] = __builtin_amdgcn_mfma_f32_16x16x32_f16(afrag, bfrag, acc[dt], 0, 0, 0);
            }
        }
        __syncthreads();
    }

    #pragma unroll
    for (int dt = 0; dt < 4; ++dt) {
        #pragma unroll
        for (int reg = 0; reg < 4; ++reg) {
            int i = ibase + quad * 4 + reg;
            int d = dt * 16 + m;
            float v = acc[dt][reg];
            v = v > 0.f ? v : expm1f(v);  // ELU
            out[((size_t)(b * N_ + i)) * (H_ * D_) + h * D_ + d] = v;
        }
    }
}

extern "C" void kernel_launch(void* const* d_in, const int* in_sizes, int n_in,
                              void* d_out, int out_size, void* d_ws, size_t ws_size,
                              hipStream_t stream) {
    const float* x   = (const float*)d_in[0];
    const int*   adj = (const int*)d_in[1];
    const float* oh  = (const float*)d_in[2];
    const float* Wq  = (const float*)d_in[3];
    const float* Wk  = (const float*)d_in[4];
    const float* W   = (const float*)d_in[5];
    const float* a   = (const float*)d_in[6];
    float* out = (float*)d_out;
    char* ws = (char*)d_ws;

    float*   v1    = (float*)(ws + V1_OFF);
    float*   v2    = (float*)(ws + V2_OFF);
    float2*  E1A   = (float2*)(ws + E1A_OFF);
    float2*  E2A   = (float2*)(ws + E2A_OFF);
    float*   parts = (float*)(ws + PARTS_OFF);
    _Float16* WT   = (_Float16*)(ws + WT_OFF);
    unsigned* bits = (unsigned*)(ws + BITS_OFF);
    _Float16* WhT  = (_Float16*)(ws + WHT_OFF);

    k_pre<<<16384 + 265, 256, 0, stream>>>(adj, Wq, Wk, a, W, bits, v1, v2, WT);
    k_mid<<<2048 + 512, 256, 0, stream>>>(x, oh, v1, v2, WT, E1A, E2A, WhT);
    k_colsum<<<dim3(8, 4, 16), 256, 0, stream>>>(bits, E1A, E2A, parts);
    k_main<<<dim3(32, 4, 4), dim3(64, 4), 0, stream>>>(bits, E1A, E2A, parts, WhT, out);
}